// Round 6
// baseline (120.587 us; speedup 1.0000x reference)
//
#include <hip/hip_runtime.h>
#include <hip/hip_bf16.h>
#include <stdint.h>

typedef __attribute__((ext_vector_type(4))) float f32x4;
typedef __attribute__((ext_vector_type(8))) short s16x8;

__device__ inline short f2bf(float f) {
  union { float f; uint32_t u; } v; v.f = f;
  uint32_t r = v.u + 0x7fffu + ((v.u >> 16) & 1u);  // RNE
  return (short)(r >> 16);
}

__device__ inline void gload_lds16(const void* g, void* l) {
  __builtin_amdgcn_global_load_lds((const __attribute__((address_space(1))) void*)g,
                                   (__attribute__((address_space(3))) void*)l,
                                   16, 0, 0);
}

#define MFMA16 __builtin_amdgcn_mfma_f32_16x16x32_bf16

__device__ inline uint32_t lds_off(const void* p) {
  return (uint32_t)(uintptr_t)(const __attribute__((address_space(3))) char*)p;
}
__device__ inline s16x8 dsr_b128(uint32_t addr) {
  s16x8 r;
  asm volatile("ds_read_b128 %0, %1" : "=v"(r) : "v"(addr));
  return r;
}

// ---------------- Kernel 1: X fp32 -> bf16 ----------------
__global__ __launch_bounds__(256) void k_convert_x(const float* __restrict__ x,
                                                   short* __restrict__ xb) {
  int i = (blockIdx.x * 256 + threadIdx.x) * 8;
  const float4* p = (const float4*)(x + i);
  float4 a = p[0], b = p[1];
  s16x8 o;
  o[0] = f2bf(a.x); o[1] = f2bf(a.y); o[2] = f2bf(a.z); o[3] = f2bf(a.w);
  o[4] = f2bf(b.x); o[5] = f2bf(b.y); o[6] = f2bf(b.z); o[7] = f2bf(b.w);
  *(s16x8*)(xb + i) = o;
}

// ---------------- Kernel 2: W [K=1024][N=1024] fp32 -> Wt [3][N][K] bf16 ----------------
__global__ __launch_bounds__(256) void k_transpose_w(const float* __restrict__ qw,
                                                     const float* __restrict__ kw,
                                                     const float* __restrict__ vw,
                                                     short* __restrict__ wt) {
  __shared__ float tile[64][65];
  int a  = blockIdx.x >> 8;
  int t2 = blockIdx.x & 255;
  int k0 = (t2 >> 4) << 6;
  int n0 = (t2 & 15) << 6;
  const float* w = (a == 0) ? qw : (a == 1) ? kw : vw;
  int c = threadIdx.x & 63, rr = threadIdx.x >> 6;
#pragma unroll
  for (int i = 0; i < 16; ++i) {
    int r = i * 4 + rr;
    tile[r][c] = w[(k0 + r) * 1024 + n0 + c];
  }
  __syncthreads();
  short* o = wt + a * 1048576;
#pragma unroll
  for (int i = 0; i < 16; ++i) {
    int r = i * 4 + rr;
    o[(n0 + r) * 1024 + k0 + c] = f2bf(tile[c][r]);
  }
}

// ---------------- Kernel 3: QKV GEMM — m201-style 4-phase/K-tile interleave ----------
// C[8192][3072] = Xb[8192][1024] * Wt^T + bias, bf16 out.
// BM=256 BN=192 BK=64; 512 thr = 8 waves (2M x 4N), per-wave 128x48 (8x3 frags).
// LDS: A 3 slots x 32KB @0 (2 K-tiles ahead), B 2 slots x 24KB @98304 (1 ahead) = 144KB.
// Per K-tile: 4 phases (ks x m-half), each {ds_read 4-7 | G-load issue | barrier |
// lgkmcnt(0) | setprio(1) 12xMFMA setprio(0) | barrier}. vmcnt(4) once per K-tile
// (issue order B(t+1) THEN A(t+2) so the 4 left in flight are exactly A(t+2)).
__global__ __launch_bounds__(512, 2) void k_gemm(const short* __restrict__ xb,
                                                 const short* __restrict__ wt,
                                                 const float* __restrict__ bias3,
                                                 short* __restrict__ C) {
  __shared__ short lds[73728];  // 144 KB
  const int tid = threadIdx.x, lane = tid & 63, wv = tid >> 6;
  const int wm = wv >> 2, wn = wv & 3;
  int wg = blockIdx.x;
  wg = (wg & 7) * 64 + (wg >> 3);  // bijective XCD swizzle (512 = 8*64)
  const int mt = wg >> 4, nt = wg & 15;
  const short* asrc = xb + (size_t)(mt * 256) * 1024;
  const short* bsrc = wt + (size_t)(nt * 192) * 1024;

  // staging source offsets (pre-permuted; LDS dest linear; logical slot s at phys s^(r&7))
  int srcA[4], srcB[3];
#pragma unroll
  for (int i = 0; i < 4; ++i) {
    int c = i * 512 + tid, r = c >> 3, ss = c & 7;
    srcA[i] = r * 1024 + (ss ^ (r & 7)) * 8;
  }
#pragma unroll
  for (int i = 0; i < 3; ++i) {
    int c = i * 512 + tid, r = c >> 3, ss = c & 7;
    srcB[i] = r * 1024 + (ss ^ (r & 7)) * 8;
  }

  // fragment base addresses (phys slot XOR depends only on lane)
  const uint32_t ldsb = lds_off(lds);
  const uint32_t slot0 = ((uint32_t)((lane >> 4) ^ (lane & 7))) << 4;
  const uint32_t Ab0 = ldsb + (uint32_t)(wm * 128 + (lane & 15)) * 128 + slot0;
  const uint32_t Ab1 = Ab0 ^ 64;
  const uint32_t Bb0 = ldsb + 98304 + (uint32_t)(wn * 48 + (lane & 15)) * 128 + slot0;
  const uint32_t Bb1 = Bb0 ^ 64;

  f32x4 acc[8][3] = {};

  auto STAGE_A2 = [&](int t, int slot, int half) {
    const short* at = asrc + t * 64;
    char* l = (char*)lds + slot * 32768;
#pragma unroll
    for (int i = half * 2; i < half * 2 + 2; ++i)
      gload_lds16(at + srcA[i], l + (i * 512 + tid) * 16);
  };
  auto STAGE_B = [&](int t, int slot) {
    const short* bt = bsrc + t * 64;
    char* l = (char*)lds + 98304 + slot * 24576;
#pragma unroll
    for (int i = 0; i < 3; ++i) gload_lds16(bt + srcB[i], l + (i * 512 + tid) * 16);
  };

  // prologue: B(0), A(0), A(1); vmcnt(4) leaves exactly A(1) in flight
  STAGE_B(0, 0);
  STAGE_A2(0, 0, 0); STAGE_A2(0, 0, 1);
  STAGE_A2(1, 1, 0); STAGE_A2(1, 1, 1);
  asm volatile("s_waitcnt vmcnt(4)" ::: "memory");
  __builtin_amdgcn_s_barrier();

  for (int kt = 0; kt < 16; ++kt) {
    const uint32_t aS = (uint32_t)((kt % 3) * 32768);
    const uint32_t bS = (uint32_t)((kt & 1) * 24576);
    const uint32_t a0 = Ab0 + aS, a1 = Ab1 + aS;
    const uint32_t b0 = Bb0 + bS, b1 = Bb1 + bS;
    s16x8 af[4], bf[3];

    // ---- phase 0: ks=0, mh=0 (+ stage B(kt+1)) ----
    bf[0] = dsr_b128(b0); bf[1] = dsr_b128(b0 + 2048); bf[2] = dsr_b128(b0 + 4096);
    af[0] = dsr_b128(a0); af[1] = dsr_b128(a0 + 2048);
    af[2] = dsr_b128(a0 + 4096); af[3] = dsr_b128(a0 + 6144);
    if (kt < 15) STAGE_B(kt + 1, (kt + 1) & 1);
    __builtin_amdgcn_s_barrier();
    asm volatile("s_waitcnt lgkmcnt(0)" ::: "memory");
    __builtin_amdgcn_sched_barrier(0);
    __builtin_amdgcn_s_setprio(1);
#pragma unroll
    for (int m = 0; m < 4; ++m)
#pragma unroll
      for (int n = 0; n < 3; ++n)
        acc[m][n] = MFMA16(af[m], bf[n], acc[m][n], 0, 0, 0);
    __builtin_amdgcn_s_setprio(0);
    __builtin_amdgcn_s_barrier();

    // ---- phase 1: ks=0, mh=1 (+ stage A(kt+2) half 0) ----
    af[0] = dsr_b128(a0 + 8192);  af[1] = dsr_b128(a0 + 10240);
    af[2] = dsr_b128(a0 + 12288); af[3] = dsr_b128(a0 + 14336);
    if (kt < 14) STAGE_A2(kt + 2, (kt + 2) % 3, 0);
    __builtin_amdgcn_s_barrier();
    asm volatile("s_waitcnt lgkmcnt(0)" ::: "memory");
    __builtin_amdgcn_sched_barrier(0);
    __builtin_amdgcn_s_setprio(1);
#pragma unroll
    for (int m = 0; m < 4; ++m)
#pragma unroll
      for (int n = 0; n < 3; ++n)
        acc[m + 4][n] = MFMA16(af[m], bf[n], acc[m + 4][n], 0, 0, 0);
    __builtin_amdgcn_s_setprio(0);
    __builtin_amdgcn_s_barrier();

    // ---- phase 2: ks=1, mh=0 (+ stage A(kt+2) half 1) ----
    bf[0] = dsr_b128(b1); bf[1] = dsr_b128(b1 + 2048); bf[2] = dsr_b128(b1 + 4096);
    af[0] = dsr_b128(a1); af[1] = dsr_b128(a1 + 2048);
    af[2] = dsr_b128(a1 + 4096); af[3] = dsr_b128(a1 + 6144);
    if (kt < 14) STAGE_A2(kt + 2, (kt + 2) % 3, 1);
    __builtin_amdgcn_s_barrier();
    asm volatile("s_waitcnt lgkmcnt(0)" ::: "memory");
    __builtin_amdgcn_sched_barrier(0);
    __builtin_amdgcn_s_setprio(1);
#pragma unroll
    for (int m = 0; m < 4; ++m)
#pragma unroll
      for (int n = 0; n < 3; ++n)
        acc[m][n] = MFMA16(af[m], bf[n], acc[m][n], 0, 0, 0);
    __builtin_amdgcn_s_setprio(0);
    __builtin_amdgcn_s_barrier();

    // ---- phase 3: ks=1, mh=1 (+ per-K-tile vmcnt before trailing barrier) ----
    af[0] = dsr_b128(a1 + 8192);  af[1] = dsr_b128(a1 + 10240);
    af[2] = dsr_b128(a1 + 12288); af[3] = dsr_b128(a1 + 14336);
    __builtin_amdgcn_s_barrier();
    asm volatile("s_waitcnt lgkmcnt(0)" ::: "memory");
    __builtin_amdgcn_sched_barrier(0);
    __builtin_amdgcn_s_setprio(1);
#pragma unroll
    for (int m = 0; m < 4; ++m)
#pragma unroll
      for (int n = 0; n < 3; ++n)
        acc[m + 4][n] = MFMA16(af[m], bf[n], acc[m + 4][n], 0, 0, 0);
    __builtin_amdgcn_s_setprio(0);
    if (kt < 14) {
      asm volatile("s_waitcnt vmcnt(4)" ::: "memory");   // drains B(kt+1)+A(kt+1); leaves A(kt+2)
    } else if (kt == 14) {
      asm volatile("s_waitcnt vmcnt(0)" ::: "memory");   // tail: drain everything
    }
    __builtin_amdgcn_s_barrier();
  }

  // epilogue: bias + bf16 store into fused C (row stride 3072)
  int nbase = nt * 192 + wn * 48;
  int mbase = mt * 256 + wm * 128;
#pragma unroll
  for (int n = 0; n < 3; ++n) {
    int col = nbase + n * 16 + (lane & 15);
    float bv = bias3[col];
#pragma unroll
    for (int m = 0; m < 8; ++m)
#pragma unroll
      for (int r = 0; r < 4; ++r) {
        int mm = mbase + m * 16 + ((lane >> 4) << 2) + r;
        C[(size_t)mm * 3072 + col] = f2bf(acc[m][n][r] + bv);
      }
  }
}

// ---------------- Kernel 4: block-local attention (stride 3072, unchanged) ----------
__global__ __launch_bounds__(512) void k_attn(const short* __restrict__ QKV,
                                              const int* __restrict__ perm,
                                              float* __restrict__ out) {
  __shared__ short Qs[256 * 64];
  __shared__ short Ks[256 * 64];
  __shared__ short Vs[64 * 256];
  __shared__ short Ps[8 * 1024];

  int tid = threadIdx.x;
  int lane = tid & 63, wv = tid >> 6;
  int bx = blockIdx.x;
  int b = bx >> 8, g = (bx >> 4) & 15, n = bx & 15;
  int p = perm[g * 16 + n];
  int pg = p >> 4, ph = p & 15;

  const short* qsrc = QKV + (size_t)(b * 4096 + g * 256) * 3072 + n * 64;
  const short* ksrc = QKV + (size_t)(b * 4096 + pg * 256) * 3072 + 1024 + ph * 64;
  const short* vsrc = QKV + (size_t)(b * 4096 + pg * 256) * 3072 + 2048 + ph * 64;

  s16x8 vreg[4];
#pragma unroll
  for (int i = 0; i < 4; ++i) {
    int c = i * 512 + tid;
    int t = c >> 3;
    int d0 = (c & 7) << 3;
    vreg[i] = *(const s16x8*)(vsrc + t * 3072 + d0);
  }
#pragma unroll
  for (int i = 0; i < 4; ++i) {
    int c = i * 512 + tid;
    int row = c >> 3;
    int colb = (c & 7) << 4;
    int sc = colb ^ ((row & 7) << 4);
    gload_lds16(qsrc + row * 3072 + (sc >> 1), (char*)Qs + c * 16);
    gload_lds16(ksrc + row * 3072 + (sc >> 1), (char*)Ks + c * 16);
  }
#pragma unroll
  for (int i = 0; i < 4; ++i) {
    int c = i * 512 + tid;
    int t = c >> 3;
    int d0 = (c & 7) << 3;
#pragma unroll
    for (int j = 0; j < 8; ++j) {
      int d = d0 + j;
      int sl = (d & 7) ^ ((d >> 3) & 7);
      int by = d * 512 + ((t * 2) ^ (sl << 4));
      *(short*)((char*)Vs + by) = vreg[i][j];
    }
  }
  __syncthreads();

  int qr0 = wv * 32;
  f32x4 accS[2][16] = {};
#pragma unroll
  for (int ks = 0; ks < 2; ++ks) {
    int cb = (ks << 6) + ((lane >> 4) << 4);
    s16x8 aq[2];
#pragma unroll
    for (int rf = 0; rf < 2; ++rf) {
      int row = qr0 + rf * 16 + (lane & 15);
      aq[rf] = *(const s16x8*)((const char*)Qs + row * 128 + (cb ^ ((row & 7) << 4)));
    }
#pragma unroll
    for (int cf = 0; cf < 16; ++cf) {
      int row = cf * 16 + (lane & 15);
      s16x8 bk = *(const s16x8*)((const char*)Ks + row * 128 + (cb ^ ((row & 7) << 4)));
      accS[0][cf] = MFMA16(aq[0], bk, accS[0][cf], 0, 0, 0);
      accS[1][cf] = MFMA16(aq[1], bk, accS[1][cf], 0, 0, 0);
    }
  }

  const float sc_log2e = 0.125f * 1.44269504088896f;
  float mx[2][4], inv[2][4];
#pragma unroll
  for (int rf = 0; rf < 2; ++rf)
#pragma unroll
    for (int r = 0; r < 4; ++r) {
      float m_ = accS[rf][0][r];
#pragma unroll
      for (int cf = 1; cf < 16; ++cf) m_ = fmaxf(m_, accS[rf][cf][r]);
#pragma unroll
      for (int msk = 1; msk < 16; msk <<= 1) m_ = fmaxf(m_, __shfl_xor(m_, msk));
      mx[rf][r] = m_;
    }
#pragma unroll
  for (int rf = 0; rf < 2; ++rf)
#pragma unroll
    for (int r = 0; r < 4; ++r) {
      float s_ = 0.f;
#pragma unroll
      for (int cf = 0; cf < 16; ++cf) {
        float e = exp2f((accS[rf][cf][r] - mx[rf][r]) * sc_log2e);
        accS[rf][cf][r] = e;
        s_ += e;
      }
#pragma unroll
      for (int msk = 1; msk < 16; msk <<= 1) s_ += __shfl_xor(s_, msk);
      inv[rf][r] = 1.0f / s_;
    }

  f32x4 accO[2][4] = {};
  short* pchunk = Ps + wv * 1024;
#pragma unroll
  for (int ks = 0; ks < 8; ++ks) {
#pragma unroll
    for (int rf = 0; rf < 2; ++rf)
#pragma unroll
      for (int half = 0; half < 2; ++half) {
        int cf = ks * 2 + half;
        int kvl = half * 16 + (lane & 15);
        int qp = (lane >> 4) << 2;
        int base = rf * 512 + ((kvl >> 3) << 7) + (kvl & 7);
#pragma unroll
        for (int r = 0; r < 4; ++r)
          pchunk[base + (qp + r) * 8] = f2bf(accS[rf][cf][r]);
      }
    int cbv = (ks << 6) + ((lane >> 4) << 4);
#pragma unroll
    for (int rf = 0; rf < 2; ++rf) {
      s16x8 ap = *(const s16x8*)(pchunk + rf * 512 + lane * 8);
#pragma unroll
      for (int dc = 0; dc < 4; ++dc) {
        int vrow = dc * 16 + (lane & 15);
        int sl = (vrow & 7) ^ ((vrow >> 3) & 7);
        s16x8 bv = *(const s16x8*)((const char*)Vs + vrow * 512 + (cbv ^ (sl << 4)));
        accO[rf][dc] = MFMA16(ap, bv, accO[rf][dc], 0, 0, 0);
      }
    }
  }

#pragma unroll
  for (int rf = 0; rf < 2; ++rf)
#pragma unroll
    for (int dc = 0; dc < 4; ++dc)
#pragma unroll
      for (int r = 0; r < 4; ++r) {
        int q = qr0 + rf * 16 + ((lane >> 4) << 2) + r;
        int d = dc * 16 + (lane & 15);
        out[(size_t)((b * 4096 + g * 256 + q) * 16 + n) * 64 + d] = accO[rf][dc][r] * inv[rf][r];
      }
}

extern "C" void kernel_launch(void* const* d_in, const int* in_sizes, int n_in,
                              void* d_out, int out_size, void* d_ws, size_t ws_size,
                              hipStream_t stream) {
  const float* x    = (const float*)d_in[0];
  const int*   perm = (const int*)d_in[2];
  const float* qw   = (const float*)d_in[3];
  const float* qb   = (const float*)d_in[4];
  const float* kw   = (const float*)d_in[5];
  const float* kb   = (const float*)d_in[6];
  const float* vw   = (const float*)d_in[7];
  const float* vb   = (const float*)d_in[8];
  float* out = (float*)d_out;

  char* ws = (char*)d_ws;
  short* Xb    = (short*)(ws);                   // 16 MB [8192][1024] bf16
  short* Wt    = (short*)(ws + 16777216UL);      //  6 MB [3072 n][1024 k] bf16
  short* C     = (short*)(ws + 23068672UL);      // 48 MB [8192][3072] bf16 (Q|K|V fused)
  float* bias3 = (float*)(ws + 73400320UL);      // 12 KB [3072] f32

  hipMemcpyAsync(bias3,        qb, 4096, hipMemcpyDeviceToDevice, stream);
  hipMemcpyAsync(bias3 + 1024, kb, 4096, hipMemcpyDeviceToDevice, stream);
  hipMemcpyAsync(bias3 + 2048, vb, 4096, hipMemcpyDeviceToDevice, stream);

  k_convert_x<<<4096, 256, 0, stream>>>(x, Xb);
  k_transpose_w<<<768, 256, 0, stream>>>(qw, kw, vw, Wt);
  k_gemm<<<512, 512, 0, stream>>>(Xb, Wt, bias3, C);
  k_attn<<<512, 512, 0, stream>>>(C, perm, out);
}

// Round 7
// 101.294 us; speedup vs baseline: 1.1905x; 1.1905x over previous
//
#include <hip/hip_runtime.h>
#include <hip/hip_bf16.h>
#include <stdint.h>

typedef __attribute__((ext_vector_type(4))) float f32x4;
typedef __attribute__((ext_vector_type(8))) short s16x8;

__device__ inline short f2bf(float f) {
  union { float f; uint32_t u; } v; v.f = f;
  uint32_t r = v.u + 0x7fffu + ((v.u >> 16) & 1u);  // RNE
  return (short)(r >> 16);
}

__device__ inline void gload_lds16(const void* g, void* l) {
  __builtin_amdgcn_global_load_lds((const __attribute__((address_space(1))) void*)g,
                                   (__attribute__((address_space(3))) void*)l,
                                   16, 0, 0);
}

#define MFMA16 __builtin_amdgcn_mfma_f32_16x16x32_bf16

// ---------------- Kernel 1: X fp32 -> bf16 ----------------
__global__ __launch_bounds__(256) void k_convert_x(const float* __restrict__ x,
                                                   short* __restrict__ xb) {
  int i = (blockIdx.x * 256 + threadIdx.x) * 8;
  const float4* p = (const float4*)(x + i);
  float4 a = p[0], b = p[1];
  s16x8 o;
  o[0] = f2bf(a.x); o[1] = f2bf(a.y); o[2] = f2bf(a.z); o[3] = f2bf(a.w);
  o[4] = f2bf(b.x); o[5] = f2bf(b.y); o[6] = f2bf(b.z); o[7] = f2bf(b.w);
  *(s16x8*)(xb + i) = o;
}

// ---------------- Kernel 2: W [K=1024][N=1024] fp32 -> Wt [3][N][K] bf16 ----------------
__global__ __launch_bounds__(256) void k_transpose_w(const float* __restrict__ qw,
                                                     const float* __restrict__ kw,
                                                     const float* __restrict__ vw,
                                                     short* __restrict__ wt) {
  __shared__ float tile[64][65];
  int a  = blockIdx.x >> 8;
  int t2 = blockIdx.x & 255;
  int k0 = (t2 >> 4) << 6;
  int n0 = (t2 & 15) << 6;
  const float* w = (a == 0) ? qw : (a == 1) ? kw : vw;
  int c = threadIdx.x & 63, rr = threadIdx.x >> 6;
#pragma unroll
  for (int i = 0; i < 16; ++i) {
    int r = i * 4 + rr;
    tile[r][c] = w[(k0 + r) * 1024 + n0 + c];
  }
  __syncthreads();
  short* o = wt + a * 1048576;
#pragma unroll
  for (int i = 0; i < 16; ++i) {
    int r = i * 4 + rr;
    o[(n0 + r) * 1024 + k0 + c] = f2bf(tile[c][r]);
  }
}

// ---------------- Kernel 3: QKV GEMM (exact round-3 best: 60.5us, MfmaUtil 34-36) ----
// Tile 256x128, BK=32, 4 waves (2M x 2N), per-wave 128x64 (8x4 frags).
// LDS: 3 bufs x (A 16KB + B 8KB) = 72 KB -> 2 blocks/CU. vmcnt(6) + 1 barrier / K-tile.
__global__ __launch_bounds__(256, 2) void k_gemm(const short* __restrict__ xb,
                                                 const short* __restrict__ wt,
                                                 const float* __restrict__ qbias,
                                                 const float* __restrict__ kbias,
                                                 const float* __restrict__ vbias,
                                                 short* __restrict__ Qo,
                                                 short* __restrict__ Ko,
                                                 short* __restrict__ Vo) {
  __shared__ short lds[36864];  // 72 KB
  const int tid = threadIdx.x, lane = tid & 63, wv = tid >> 6;
  const int wm = wv >> 1, wn = wv & 1;
  const int mt = blockIdx.x, by = blockIdx.y;
  const int a = by >> 3;
  const short* asrc = xb + (size_t)(mt * 256) * 1024;
  const short* bsrc = wt + (size_t)a * 1048576 + (size_t)((by & 7) * 128) * 1024;

  int srcA[4], dstA[4], srcB[2], dstB[2];
#pragma unroll
  for (int i = 0; i < 4; ++i) {
    int L = i * 256 + tid, s = L & 31;
    int row = (L >> 5) * 8 + (s >> 2);
    int c = (s & 3) ^ ((s >> 3) & 3);
    srcA[i] = row * 1024 + c * 8;
    dstA[i] = L * 16;
  }
#pragma unroll
  for (int i = 0; i < 2; ++i) {
    int L = i * 256 + tid, s = L & 31;
    int row = (L >> 5) * 8 + (s >> 2);
    int c = (s & 3) ^ ((s >> 3) & 3);
    srcB[i] = row * 1024 + c * 8;
    dstB[i] = 16384 + L * 16;
  }

  int aoff[8], boff[4];
#pragma unroll
  for (int m = 0; m < 8; ++m) {
    int row = wm * 128 + m * 16 + (lane & 15);
    aoff[m] = ((row >> 3) * 32 + (row & 7) * 4 + ((lane >> 4) ^ ((row >> 1) & 3))) * 16;
  }
#pragma unroll
  for (int n = 0; n < 4; ++n) {
    int row = wn * 64 + n * 16 + (lane & 15);
    boff[n] = 16384 + ((row >> 3) * 32 + (row & 7) * 4 + ((lane >> 4) ^ ((row >> 1) & 3))) * 16;
  }

  f32x4 acc[8][4] = {};

  auto STAGE = [&](int t, int bb) {
    const short* at = asrc + t * 32;
    const short* bt = bsrc + t * 32;
    char* l = (char*)lds + bb;
#pragma unroll
    for (int i = 0; i < 4; ++i) gload_lds16(at + srcA[i], l + dstA[i]);
#pragma unroll
    for (int i = 0; i < 2; ++i) gload_lds16(bt + srcB[i], l + dstB[i]);
  };

  STAGE(0, 0);
  STAGE(1, 24576);
  int bcur = 0, bpre = 49152;

  for (int t = 0; t < 31; ++t) {
    asm volatile("s_waitcnt vmcnt(6)" ::: "memory");
    __builtin_amdgcn_s_barrier();
    asm volatile("" ::: "memory");
    if (t < 30) STAGE(t + 2, bpre);
    const char* bufc = (const char*)lds + bcur;
    s16x8 af[8], bf[4];
#pragma unroll
    for (int m = 0; m < 8; ++m) af[m] = *(const s16x8*)(bufc + aoff[m]);
#pragma unroll
    for (int n = 0; n < 4; ++n) bf[n] = *(const s16x8*)(bufc + boff[n]);
    __builtin_amdgcn_s_setprio(1);
#pragma unroll
    for (int m = 0; m < 8; ++m)
#pragma unroll
      for (int n = 0; n < 4; ++n)
        acc[m][n] = MFMA16(af[m], bf[n], acc[m][n], 0, 0, 0);
    __builtin_amdgcn_s_setprio(0);
    bcur += 24576; if (bcur == 73728) bcur = 0;
    bpre += 24576; if (bpre == 73728) bpre = 0;
  }
  asm volatile("s_waitcnt vmcnt(0)" ::: "memory");
  __builtin_amdgcn_s_barrier();
  asm volatile("" ::: "memory");
  {
    const char* bufc = (const char*)lds + bcur;
    s16x8 af[8], bf[4];
#pragma unroll
    for (int m = 0; m < 8; ++m) af[m] = *(const s16x8*)(bufc + aoff[m]);
#pragma unroll
    for (int n = 0; n < 4; ++n) bf[n] = *(const s16x8*)(bufc + boff[n]);
    __builtin_amdgcn_s_setprio(1);
#pragma unroll
    for (int m = 0; m < 8; ++m)
#pragma unroll
      for (int n = 0; n < 4; ++n)
        acc[m][n] = MFMA16(af[m], bf[n], acc[m][n], 0, 0, 0);
    __builtin_amdgcn_s_setprio(0);
  }

  const float* bias = (a == 0) ? qbias : (a == 1) ? kbias : vbias;
  short* outp = (a == 0) ? Qo : (a == 1) ? Ko : Vo;
  int nbase = (by & 7) * 128 + wn * 64;
  int mbase = mt * 256 + wm * 128;
#pragma unroll
  for (int n = 0; n < 4; ++n) {
    int nloc = nbase + n * 16 + (lane & 15);
    float bv = bias[nloc];
#pragma unroll
    for (int m = 0; m < 8; ++m)
#pragma unroll
      for (int r = 0; r < 4; ++r) {
        int mm = mbase + m * 16 + ((lane >> 4) << 2) + r;
        outp[(size_t)mm * 1024 + nloc] = f2bf(acc[m][n][r] + bv);
      }
  }
}

// ---------------- Kernel 4: attention — 2 q-halves/block-tile, 2 blocks/CU ----------
// 1024 blocks x 256 thr (4 waves x 32 q-rows). LDS 80KB: K 32 + V^T 32 + Q/P overlay 16.
// XCD swizzle pairs the two halves of each (b,g,n) on one XCD so K/V re-read L2-hits.
__global__ __launch_bounds__(256, 2) void k_attn(const short* __restrict__ Qb,
                                                 const short* __restrict__ Kb,
                                                 const short* __restrict__ Vb,
                                                 const int* __restrict__ perm,
                                                 float* __restrict__ out) {
  __shared__ short Ks[256 * 64];   // [kv-token][d], XOR-swizzled rows (32 KB)
  __shared__ short Vs[64 * 256];   // [d][kv-token], (d,t)-swizzled     (32 KB)
  __shared__ short QP[8192];       // Q-half [128][64] then per-wave P  (16 KB)

  int tid = threadIdx.x;
  int lane = tid & 63, wv = tid >> 6;
  int bx = blockIdx.x;
  int wg = (bx & 7) * 128 + (bx >> 3);  // bijective; logical pairs <- same XCD
  int b = wg >> 9, g = (wg >> 5) & 15, n = (wg >> 1) & 15, h = wg & 1;
  int p = perm[g * 16 + n];
  int pg = p >> 4, ph = p & 15;

  const short* qsrc = Qb + (size_t)(b * 4096 + g * 256 + h * 128) * 1024 + n * 64;
  const short* ksrc = Kb + (size_t)(b * 4096 + pg * 256) * 1024 + ph * 64;
  const short* vsrc = Vb + (size_t)(b * 4096 + pg * 256) * 1024 + ph * 64;

  // V loads to regs (overlap with Q/K gload_lds staging)
  s16x8 vreg[8];
#pragma unroll
  for (int i = 0; i < 8; ++i) {
    int c = i * 256 + tid;
    int t = c >> 3;
    int d0 = (c & 7) << 3;
    vreg[i] = *(const s16x8*)(vsrc + t * 1024 + d0);
  }
  // stage Q (128 rows) and K (256 rows), pre-swizzled source, linear LDS dest
#pragma unroll
  for (int i = 0; i < 4; ++i) {
    int c = i * 256 + tid;
    int row = c >> 3;
    int sc = ((c & 7) << 4) ^ ((row & 7) << 4);
    gload_lds16(qsrc + row * 1024 + (sc >> 1), (char*)QP + c * 16);
  }
#pragma unroll
  for (int i = 0; i < 8; ++i) {
    int c = i * 256 + tid;
    int row = c >> 3;
    int sc = ((c & 7) << 4) ^ ((row & 7) << 4);
    gload_lds16(ksrc + row * 1024 + (sc >> 1), (char*)Ks + c * 16);
  }
  // V^T scalar writes, conflict-free (d,t) swizzle
#pragma unroll
  for (int i = 0; i < 8; ++i) {
    int c = i * 256 + tid;
    int t = c >> 3;
    int d0 = (c & 7) << 3;
#pragma unroll
    for (int j = 0; j < 8; ++j) {
      int d = d0 + j;
      int sl = (d & 7) ^ ((d >> 3) & 7);
      int by = d * 512 + ((t * 2) ^ (sl << 4));
      *(short*)((char*)Vs + by) = vreg[i][j];
    }
  }
  __syncthreads();

  int qr0 = wv * 32;  // within the 128-row half
  // ---- QK^T: 32 q-rows x 256 kv ----
  f32x4 accS[2][16] = {};
#pragma unroll
  for (int ks = 0; ks < 2; ++ks) {
    int cb = (ks << 6) + ((lane >> 4) << 4);
    s16x8 aq[2];
#pragma unroll
    for (int rf = 0; rf < 2; ++rf) {
      int row = qr0 + rf * 16 + (lane & 15);
      aq[rf] = *(const s16x8*)((const char*)QP + row * 128 + (cb ^ ((row & 7) << 4)));
    }
#pragma unroll
    for (int cf = 0; cf < 16; ++cf) {
      int row = cf * 16 + (lane & 15);
      s16x8 bk = *(const s16x8*)((const char*)Ks + row * 128 + (cb ^ ((row & 7) << 4)));
      accS[0][cf] = MFMA16(aq[0], bk, accS[0][cf], 0, 0, 0);
      accS[1][cf] = MFMA16(aq[1], bk, accS[1][cf], 0, 0, 0);
    }
  }

  // ---- wave-parallel softmax ----
  const float sc_log2e = 0.125f * 1.44269504088896f;
  float mx[2][4], inv[2][4];
#pragma unroll
  for (int rf = 0; rf < 2; ++rf)
#pragma unroll
    for (int r = 0; r < 4; ++r) {
      float m_ = accS[rf][0][r];
#pragma unroll
      for (int cf = 1; cf < 16; ++cf) m_ = fmaxf(m_, accS[rf][cf][r]);
#pragma unroll
      for (int msk = 1; msk < 16; msk <<= 1) m_ = fmaxf(m_, __shfl_xor(m_, msk));
      mx[rf][r] = m_;
    }
#pragma unroll
  for (int rf = 0; rf < 2; ++rf)
#pragma unroll
    for (int r = 0; r < 4; ++r) {
      float s_ = 0.f;
#pragma unroll
      for (int cf = 0; cf < 16; ++cf) {
        float e = exp2f((accS[rf][cf][r] - mx[rf][r]) * sc_log2e);
        accS[rf][cf][r] = e;
        s_ += e;
      }
#pragma unroll
      for (int msk = 1; msk < 16; msk <<= 1) s_ += __shfl_xor(s_, msk);
      inv[rf][r] = 1.0f / s_;
    }

  // Q region dead for ALL waves; reuse as P buffer
  __syncthreads();

  // ---- PV: per 32-kv tile, relayout P through wave-private LDS chunk ----
  f32x4 accO[2][4] = {};
  short* pchunk = QP + wv * 1024;
#pragma unroll
  for (int ks = 0; ks < 8; ++ks) {
#pragma unroll
    for (int rf = 0; rf < 2; ++rf)
#pragma unroll
      for (int half = 0; half < 2; ++half) {
        int cf = ks * 2 + half;
        int kvl = half * 16 + (lane & 15);
        int qp = (lane >> 4) << 2;
        int base = rf * 512 + ((kvl >> 3) << 7) + (kvl & 7);
#pragma unroll
        for (int r = 0; r < 4; ++r)
          pchunk[base + (qp + r) * 8] = f2bf(accS[rf][cf][r]);
      }
    int cbv = (ks << 6) + ((lane >> 4) << 4);
#pragma unroll
    for (int rf = 0; rf < 2; ++rf) {
      s16x8 ap = *(const s16x8*)(pchunk + rf * 512 + lane * 8);
#pragma unroll
      for (int dc = 0; dc < 4; ++dc) {
        int vrow = dc * 16 + (lane & 15);
        int sl = (vrow & 7) ^ ((vrow >> 3) & 7);
        s16x8 bv = *(const s16x8*)((const char*)Vs + vrow * 512 + (cbv ^ (sl << 4)));
        accO[rf][dc] = MFMA16(ap, bv, accO[rf][dc], 0, 0, 0);
      }
    }
  }

  // ---- epilogue ----
#pragma unroll
  for (int rf = 0; rf < 2; ++rf)
#pragma unroll
    for (int dc = 0; dc < 4; ++dc)
#pragma unroll
      for (int r = 0; r < 4; ++r) {
        int q = h * 128 + qr0 + rf * 16 + ((lane >> 4) << 2) + r;
        int d = dc * 16 + (lane & 15);
        out[(size_t)((b * 4096 + g * 256 + q) * 16 + n) * 64 + d] = accO[rf][dc][r] * inv[rf][r];
      }
}

extern "C" void kernel_launch(void* const* d_in, const int* in_sizes, int n_in,
                              void* d_out, int out_size, void* d_ws, size_t ws_size,
                              hipStream_t stream) {
  const float* x    = (const float*)d_in[0];
  const int*   perm = (const int*)d_in[2];
  const float* qw   = (const float*)d_in[3];
  const float* qb   = (const float*)d_in[4];
  const float* kw   = (const float*)d_in[5];
  const float* kb   = (const float*)d_in[6];
  const float* vw   = (const float*)d_in[7];
  const float* vb   = (const float*)d_in[8];
  float* out = (float*)d_out;

  char* ws = (char*)d_ws;
  short* Xb = (short*)(ws);                         // 16 MB  [8192][1024] bf16
  short* Wt = (short*)(ws + 16777216UL);            //  6 MB  [3][1024 n][1024 k] bf16
  short* Qb = (short*)(ws + 23068672UL);            // 16 MB
  short* Kb = (short*)(ws + 39845888UL);            // 16 MB
  short* Vb = (short*)(ws + 56623104UL);            // 16 MB

  k_convert_x<<<4096, 256, 0, stream>>>(x, Xb);
  k_transpose_w<<<768, 256, 0, stream>>>(qw, kw, vw, Wt);
  k_gemm<<<dim3(32, 24), 256, 0, stream>>>(Xb, Wt, qb, kb, vb, Qb, Kb, Vb);
  k_attn<<<1024, 256, 0, stream>>>(Qb, Kb, Vb, perm, out);
}

// Round 8
// 99.562 us; speedup vs baseline: 1.2112x; 1.0174x over previous
//
#include <hip/hip_runtime.h>
#include <hip/hip_bf16.h>
#include <stdint.h>

typedef __attribute__((ext_vector_type(4))) float f32x4;
typedef __attribute__((ext_vector_type(8))) short s16x8;

__device__ inline short f2bf(float f) {
  union { float f; uint32_t u; } v; v.f = f;
  uint32_t r = v.u + 0x7fffu + ((v.u >> 16) & 1u);  // RNE
  return (short)(r >> 16);
}

__device__ inline void gload_lds16(const void* g, void* l) {
  __builtin_amdgcn_global_load_lds((const __attribute__((address_space(1))) void*)g,
                                   (__attribute__((address_space(3))) void*)l,
                                   16, 0, 0);
}

#define MFMA16 __builtin_amdgcn_mfma_f32_16x16x32_bf16

// ---------------- Kernel 1: fused prep — X convert (blocks 0..4095) + W transpose ----
__global__ __launch_bounds__(256) void k_prep(const float* __restrict__ x,
                                              short* __restrict__ xb,
                                              const float* __restrict__ qw,
                                              const float* __restrict__ kw,
                                              const float* __restrict__ vw,
                                              short* __restrict__ wt) {
  __shared__ float tile[64][65];
  int bx = blockIdx.x;
  if (bx < 4096) {
    int i = (bx * 256 + threadIdx.x) * 8;
    const float4* p = (const float4*)(x + i);
    float4 a = p[0], b = p[1];
    s16x8 o;
    o[0] = f2bf(a.x); o[1] = f2bf(a.y); o[2] = f2bf(a.z); o[3] = f2bf(a.w);
    o[4] = f2bf(b.x); o[5] = f2bf(b.y); o[6] = f2bf(b.z); o[7] = f2bf(b.w);
    *(s16x8*)(xb + i) = o;
    return;
  }
  bx -= 4096;
  int a  = bx >> 8;
  int t2 = bx & 255;
  int k0 = (t2 >> 4) << 6;
  int n0 = (t2 & 15) << 6;
  const float* w = (a == 0) ? qw : (a == 1) ? kw : vw;
  int c = threadIdx.x & 63, rr = threadIdx.x >> 6;
#pragma unroll
  for (int i = 0; i < 16; ++i) {
    int r = i * 4 + rr;
    tile[r][c] = w[(k0 + r) * 1024 + n0 + c];
  }
  __syncthreads();
  short* o = wt + a * 1048576;
#pragma unroll
  for (int i = 0; i < 16; ++i) {
    int r = i * 4 + rr;
    o[(n0 + r) * 1024 + k0 + c] = f2bf(tile[c][r]);
  }
}

// ---------------- Kernel 2: QKV GEMM (frozen round-3 best: 60.5us, MfmaUtil 35) -------
// Tile 256x128, BK=32, 4 waves (2M x 2N), per-wave 128x64 (8x4 frags).
// LDS: 3 bufs x (A 16KB + B 8KB) = 72 KB -> 2 blocks/CU. vmcnt(6) + 1 barrier / K-tile.
__global__ __launch_bounds__(256, 2) void k_gemm(const short* __restrict__ xb,
                                                 const short* __restrict__ wt,
                                                 const float* __restrict__ qbias,
                                                 const float* __restrict__ kbias,
                                                 const float* __restrict__ vbias,
                                                 short* __restrict__ Qo,
                                                 short* __restrict__ Ko,
                                                 short* __restrict__ Vo) {
  __shared__ short lds[36864];  // 72 KB
  const int tid = threadIdx.x, lane = tid & 63, wv = tid >> 6;
  const int wm = wv >> 1, wn = wv & 1;
  const int mt = blockIdx.x, by = blockIdx.y;
  const int a = by >> 3;
  const short* asrc = xb + (size_t)(mt * 256) * 1024;
  const short* bsrc = wt + (size_t)a * 1048576 + (size_t)((by & 7) * 128) * 1024;

  int srcA[4], dstA[4], srcB[2], dstB[2];
#pragma unroll
  for (int i = 0; i < 4; ++i) {
    int L = i * 256 + tid, s = L & 31;
    int row = (L >> 5) * 8 + (s >> 2);
    int c = (s & 3) ^ ((s >> 3) & 3);
    srcA[i] = row * 1024 + c * 8;
    dstA[i] = L * 16;
  }
#pragma unroll
  for (int i = 0; i < 2; ++i) {
    int L = i * 256 + tid, s = L & 31;
    int row = (L >> 5) * 8 + (s >> 2);
    int c = (s & 3) ^ ((s >> 3) & 3);
    srcB[i] = row * 1024 + c * 8;
    dstB[i] = 16384 + L * 16;
  }

  int aoff[8], boff[4];
#pragma unroll
  for (int m = 0; m < 8; ++m) {
    int row = wm * 128 + m * 16 + (lane & 15);
    aoff[m] = ((row >> 3) * 32 + (row & 7) * 4 + ((lane >> 4) ^ ((row >> 1) & 3))) * 16;
  }
#pragma unroll
  for (int n = 0; n < 4; ++n) {
    int row = wn * 64 + n * 16 + (lane & 15);
    boff[n] = 16384 + ((row >> 3) * 32 + (row & 7) * 4 + ((lane >> 4) ^ ((row >> 1) & 3))) * 16;
  }

  f32x4 acc[8][4] = {};

  auto STAGE = [&](int t, int bb) {
    const short* at = asrc + t * 32;
    const short* bt = bsrc + t * 32;
    char* l = (char*)lds + bb;
#pragma unroll
    for (int i = 0; i < 4; ++i) gload_lds16(at + srcA[i], l + dstA[i]);
#pragma unroll
    for (int i = 0; i < 2; ++i) gload_lds16(bt + srcB[i], l + dstB[i]);
  };

  STAGE(0, 0);
  STAGE(1, 24576);
  int bcur = 0, bpre = 49152;

  for (int t = 0; t < 31; ++t) {
    asm volatile("s_waitcnt vmcnt(6)" ::: "memory");
    __builtin_amdgcn_s_barrier();
    asm volatile("" ::: "memory");
    if (t < 30) STAGE(t + 2, bpre);
    const char* bufc = (const char*)lds + bcur;
    s16x8 af[8], bf[4];
#pragma unroll
    for (int m = 0; m < 8; ++m) af[m] = *(const s16x8*)(bufc + aoff[m]);
#pragma unroll
    for (int n = 0; n < 4; ++n) bf[n] = *(const s16x8*)(bufc + boff[n]);
    __builtin_amdgcn_s_setprio(1);
#pragma unroll
    for (int m = 0; m < 8; ++m)
#pragma unroll
      for (int n = 0; n < 4; ++n)
        acc[m][n] = MFMA16(af[m], bf[n], acc[m][n], 0, 0, 0);
    __builtin_amdgcn_s_setprio(0);
    bcur += 24576; if (bcur == 73728) bcur = 0;
    bpre += 24576; if (bpre == 73728) bpre = 0;
  }
  asm volatile("s_waitcnt vmcnt(0)" ::: "memory");
  __builtin_amdgcn_s_barrier();
  asm volatile("" ::: "memory");
  {
    const char* bufc = (const char*)lds + bcur;
    s16x8 af[8], bf[4];
#pragma unroll
    for (int m = 0; m < 8; ++m) af[m] = *(const s16x8*)(bufc + aoff[m]);
#pragma unroll
    for (int n = 0; n < 4; ++n) bf[n] = *(const s16x8*)(bufc + boff[n]);
    __builtin_amdgcn_s_setprio(1);
#pragma unroll
    for (int m = 0; m < 8; ++m)
#pragma unroll
      for (int n = 0; n < 4; ++n)
        acc[m][n] = MFMA16(af[m], bf[n], acc[m][n], 0, 0, 0);
    __builtin_amdgcn_s_setprio(0);
  }

  const float* bias = (a == 0) ? qbias : (a == 1) ? kbias : vbias;
  short* outp = (a == 0) ? Qo : (a == 1) ? Ko : Vo;
  int nbase = (by & 7) * 128 + wn * 64;
  int mbase = mt * 256 + wm * 128;
#pragma unroll
  for (int n = 0; n < 4; ++n) {
    int nloc = nbase + n * 16 + (lane & 15);
    float bv = bias[nloc];
#pragma unroll
    for (int m = 0; m < 8; ++m)
#pragma unroll
      for (int r = 0; r < 4; ++r) {
        int mm = mbase + m * 16 + ((lane >> 4) << 2) + r;
        outp[(size_t)mm * 1024 + nloc] = f2bf(acc[m][n][r] + bv);
      }
  }
}

// ---------------- Kernel 3: attention — Q in regs, K-only pre-barrier, V^T deferred ---
// 1024 blocks x 256 thr (4 waves x 32 q-rows of a 128-row half). LDS 72KB:
// K 32 + V^T 32 + P 8 -> 2 blocks/CU. Issue order K(lds),V(reg),Q(reg);
// vmcnt(12) drains exactly K before the QK^T barrier; V^T written after QK^T.
__global__ __launch_bounds__(256, 2) void k_attn(const short* __restrict__ Qb,
                                                 const short* __restrict__ Kb,
                                                 const short* __restrict__ Vb,
                                                 const int* __restrict__ perm,
                                                 float* __restrict__ out) {
  __shared__ short Ks[256 * 64];   // [kv-token][d], XOR-swizzled rows (32 KB)
  __shared__ short Vs[64 * 256];   // [d][kv-token], (d,t)-swizzled     (32 KB)
  __shared__ short Ps[4 * 1024];   // per-wave 2KB P-fragment chunk     ( 8 KB)

  int tid = threadIdx.x;
  int lane = tid & 63, wv = tid >> 6;
  int bx = blockIdx.x;
  int wg = (bx & 7) * 128 + (bx >> 3);  // bijective; the two halves of a tile share an XCD
  int b = wg >> 9, g = (wg >> 5) & 15, n = (wg >> 1) & 15, h = wg & 1;
  int p = perm[g * 16 + n];
  int pg = p >> 4, ph = p & 15;

  const short* qsrc = Qb + (size_t)(b * 4096 + g * 256 + h * 128) * 1024 + n * 64;
  const short* ksrc = Kb + (size_t)(b * 4096 + pg * 256) * 1024 + ph * 64;
  const short* vsrc = Vb + (size_t)(b * 4096 + pg * 256) * 1024 + ph * 64;

  int qr0 = wv * 32;

  // ---- issue K direct-to-LDS first (oldest 8 vmem ops) ----
#pragma unroll
  for (int i = 0; i < 8; ++i) {
    int c = i * 256 + tid;
    int row = c >> 3;
    int sc = ((c & 7) << 4) ^ ((row & 7) << 4);
    gload_lds16(ksrc + row * 1024 + (sc >> 1), (char*)Ks + c * 16);
  }
  __builtin_amdgcn_sched_barrier(0);  // pin issue order: K before V/Q
  // ---- V to regs (8 loads) ----
  s16x8 vreg[8];
#pragma unroll
  for (int i = 0; i < 8; ++i) {
    int c = i * 256 + tid;
    int t = c >> 3;
    int d0 = (c & 7) << 3;
    vreg[i] = *(const s16x8*)(vsrc + t * 1024 + d0);
  }
  // ---- Q fragments to regs (4 loads; consumed by QK^T, compiler tracks deps) ----
  s16x8 qreg[2][2];
#pragma unroll
  for (int rf = 0; rf < 2; ++rf)
#pragma unroll
    for (int ks = 0; ks < 2; ++ks) {
      int row = qr0 + rf * 16 + (lane & 15);
      qreg[rf][ks] = *(const s16x8*)(qsrc + row * 1024 + ks * 32 + ((lane >> 4) << 3));
    }
  __builtin_amdgcn_sched_barrier(0);
  asm volatile("s_waitcnt vmcnt(12)" ::: "memory");  // K's 8 landed; V+Q still in flight
  __builtin_amdgcn_s_barrier();
  __builtin_amdgcn_sched_barrier(0);

  // ---- QK^T: 32 q-rows x 256 kv ----
  f32x4 accS[2][16] = {};
#pragma unroll
  for (int ks = 0; ks < 2; ++ks) {
    int cb = (ks << 6) + ((lane >> 4) << 4);
#pragma unroll
    for (int cf = 0; cf < 16; ++cf) {
      int row = cf * 16 + (lane & 15);
      s16x8 bk = *(const s16x8*)((const char*)Ks + row * 128 + (cb ^ ((row & 7) << 4)));
      accS[0][cf] = MFMA16(qreg[0][ks], bk, accS[0][cf], 0, 0, 0);
      accS[1][cf] = MFMA16(qreg[1][ks], bk, accS[1][cf], 0, 0, 0);
    }
  }

  // ---- V^T scalar writes (V landed during QK^T), conflict-free (d,t) swizzle ----
#pragma unroll
  for (int i = 0; i < 8; ++i) {
    int c = i * 256 + tid;
    int t = c >> 3;
    int d0 = (c & 7) << 3;
#pragma unroll
    for (int j = 0; j < 8; ++j) {
      int d = d0 + j;
      int sl = (d & 7) ^ ((d >> 3) & 7);
      int by = d * 512 + ((t * 2) ^ (sl << 4));
      *(short*)((char*)Vs + by) = vreg[i][j];
    }
  }
  __syncthreads();  // V^T visible to all waves before PV

  // ---- wave-parallel softmax ----
  const float sc_log2e = 0.125f * 1.44269504088896f;
  float mx[2][4], inv[2][4];
#pragma unroll
  for (int rf = 0; rf < 2; ++rf)
#pragma unroll
    for (int r = 0; r < 4; ++r) {
      float m_ = accS[rf][0][r];
#pragma unroll
      for (int cf = 1; cf < 16; ++cf) m_ = fmaxf(m_, accS[rf][cf][r]);
#pragma unroll
      for (int msk = 1; msk < 16; msk <<= 1) m_ = fmaxf(m_, __shfl_xor(m_, msk));
      mx[rf][r] = m_;
    }
#pragma unroll
  for (int rf = 0; rf < 2; ++rf)
#pragma unroll
    for (int r = 0; r < 4; ++r) {
      float s_ = 0.f;
#pragma unroll
      for (int cf = 0; cf < 16; ++cf) {
        float e = exp2f((accS[rf][cf][r] - mx[rf][r]) * sc_log2e);
        accS[rf][cf][r] = e;
        s_ += e;
      }
#pragma unroll
      for (int msk = 1; msk < 16; msk <<= 1) s_ += __shfl_xor(s_, msk);
      inv[rf][r] = 1.0f / s_;
    }

  // ---- PV: per 32-kv tile, relayout P through wave-private LDS chunk ----
  f32x4 accO[2][4] = {};
  short* pchunk = Ps + wv * 1024;
#pragma unroll
  for (int ks = 0; ks < 8; ++ks) {
#pragma unroll
    for (int rf = 0; rf < 2; ++rf)
#pragma unroll
      for (int half = 0; half < 2; ++half) {
        int cf = ks * 2 + half;
        int kvl = half * 16 + (lane & 15);
        int qp = (lane >> 4) << 2;
        int base = rf * 512 + ((kvl >> 3) << 7) + (kvl & 7);
#pragma unroll
        for (int r = 0; r < 4; ++r)
          pchunk[base + (qp + r) * 8] = f2bf(accS[rf][cf][r]);
      }
    int cbv = (ks << 6) + ((lane >> 4) << 4);
#pragma unroll
    for (int rf = 0; rf < 2; ++rf) {
      s16x8 ap = *(const s16x8*)(pchunk + rf * 512 + lane * 8);
#pragma unroll
      for (int dc = 0; dc < 4; ++dc) {
        int vrow = dc * 16 + (lane & 15);
        int sl = (vrow & 7) ^ ((vrow >> 3) & 7);
        s16x8 bv = *(const s16x8*)((const char*)Vs + vrow * 512 + (cbv ^ (sl << 4)));
        accO[rf][dc] = MFMA16(ap, bv, accO[rf][dc], 0, 0, 0);
      }
    }
  }

  // ---- epilogue ----
#pragma unroll
  for (int rf = 0; rf < 2; ++rf)
#pragma unroll
    for (int dc = 0; dc < 4; ++dc)
#pragma unroll
      for (int r = 0; r < 4; ++r) {
        int q = h * 128 + qr0 + rf * 16 + ((lane >> 4) << 2) + r;
        int d = dc * 16 + (lane & 15);
        out[(size_t)((b * 4096 + g * 256 + q) * 16 + n) * 64 + d] = accO[rf][dc][r] * inv[rf][r];
      }
}

extern "C" void kernel_launch(void* const* d_in, const int* in_sizes, int n_in,
                              void* d_out, int out_size, void* d_ws, size_t ws_size,
                              hipStream_t stream) {
  const float* x    = (const float*)d_in[0];
  const int*   perm = (const int*)d_in[2];
  const float* qw   = (const float*)d_in[3];
  const float* qb   = (const float*)d_in[4];
  const float* kw   = (const float*)d_in[5];
  const float* kb   = (const float*)d_in[6];
  const float* vw   = (const float*)d_in[7];
  const float* vb   = (const float*)d_in[8];
  float* out = (float*)d_out;

  char* ws = (char*)d_ws;
  short* Xb = (short*)(ws);                         // 16 MB  [8192][1024] bf16
  short* Wt = (short*)(ws + 16777216UL);            //  6 MB  [3][1024 n][1024 k] bf16
  short* Qb = (short*)(ws + 23068672UL);            // 16 MB
  short* Kb = (short*)(ws + 39845888UL);            // 16 MB
  short* Vb = (short*)(ws + 56623104UL);            // 16 MB

  k_prep<<<4864, 256, 0, stream>>>(x, Xb, qw, kw, vw, Wt);
  k_gemm<<<dim3(32, 24), 256, 0, stream>>>(Xb, Wt, qb, kb, vb, Qb, Kb, Vb);
  k_attn<<<1024, 256, 0, stream>>>(Qb, Kb, Vb, perm, out);
}